// Round 1
// baseline (282.958 us; speedup 1.0000x reference)
//
#include <hip/hip_runtime.h>

// GaborLayer: out[p][o] = sin(x[p]·W[o] + b[o]) * exp(-0.5*gamma[o]*||x[p]-mu[o]||^2)
// P = B*N = 262144 points, OUT = 256 features, IN = 3.
// Memory-bound: 256 MiB output write dominates. One wave per point:
// lane l handles out-features [4l, 4l+3] -> one float4 store per lane,
// whole wave writes one contiguous 1 KiB output row.

#define OUT_FEATURES 256

__global__ __launch_bounds__(256) void gabor_kernel(
    const float* __restrict__ x,      // (P, 3)
    const float* __restrict__ W,      // (256, 3)
    const float* __restrict__ b,      // (256,)
    const float* __restrict__ mu,     // (256, 3)
    const float* __restrict__ gamma,  // (256,)
    float* __restrict__ out,          // (P, 256)
    int P)
{
    const int lane        = threadIdx.x & 63;
    const int waveInBlock = threadIdx.x >> 6;                       // 0..3
    const int wavesPerBlk = blockDim.x >> 6;
    const int waveId      = blockIdx.x * wavesPerBlk + waveInBlock;
    const int wavesTotal  = gridDim.x * wavesPerBlk;

    const int o = lane << 2;  // 4 consecutive out-features per lane

    // Hoist per-feature constants into registers (amortized over the point loop).
    float w0[4], w1[4], w2[4], bb[4], m0[4], m1[4], m2[4], mu2s[4], gs[4];
#pragma unroll
    for (int j = 0; j < 4; ++j) {
        const int oj = o + j;
        w0[j] = W[oj * 3 + 0];
        w1[j] = W[oj * 3 + 1];
        w2[j] = W[oj * 3 + 2];
        m0[j] = mu[oj * 3 + 0];
        m1[j] = mu[oj * 3 + 1];
        m2[j] = mu[oj * 3 + 2];
        bb[j] = b[oj];
        gs[j] = -0.5f * gamma[oj];
        mu2s[j] = m0[j] * m0[j] + m1[j] * m1[j] + m2[j] * m2[j];
    }

    for (int p = waveId; p < P; p += wavesTotal) {
        // Wave-uniform address -> broadcast load from L1.
        const float x0 = x[p * 3 + 0];
        const float x1 = x[p * 3 + 1];
        const float x2 = x[p * 3 + 2];
        const float xs = x0 * x0 + x1 * x1 + x2 * x2;

        float4 r;
        float* rp = &r.x;
#pragma unroll
        for (int j = 0; j < 4; ++j) {
            const float lin   = fmaf(w0[j], x0, fmaf(w1[j], x1, fmaf(w2[j], x2, bb[j])));
            const float cross = fmaf(m0[j], x0, fmaf(m1[j], x1, m2[j] * x2));
            const float D     = xs - 2.0f * cross + mu2s[j];     // matches reference identity
            rp[j] = __sinf(lin) * __expf(gs[j] * D);
        }

        *reinterpret_cast<float4*>(out + (size_t)p * OUT_FEATURES + o) = r;
    }
}

extern "C" void kernel_launch(void* const* d_in, const int* in_sizes, int n_in,
                              void* d_out, int out_size, void* d_ws, size_t ws_size,
                              hipStream_t stream) {
    const float* x     = (const float*)d_in[0];
    const float* W     = (const float*)d_in[1];
    const float* b     = (const float*)d_in[2];
    const float* mu    = (const float*)d_in[3];
    const float* gamma = (const float*)d_in[4];
    float* out = (float*)d_out;

    const int P = in_sizes[0] / 3;  // B*N points

    // 2048 blocks x 4 waves = 8192 waves; each wave strides ~32 points.
    // Full oversubscription of 256 CUs for the memory-bound store stream.
    const int blocks = 2048;
    gabor_kernel<<<blocks, 256, 0, stream>>>(x, W, b, mu, gamma, out, P);
}

// Round 2
// 282.404 us; speedup vs baseline: 1.0020x; 1.0020x over previous
//
#include <hip/hip_runtime.h>

// GaborLayer: out[p][o] = sin(x[p]·W[o] + b[o]) * exp(-0.5*gamma[o]*||x[p]-mu[o]||^2)
// P = 262144 points, OUT = 256, IN = 3. Output = 256 MiB fp32 -> write-BW bound.
//
// R1 design: one wave owns a contiguous chunk of points; lane l owns features
// [4l,4l+3]. x loads are made wave-uniform (readfirstlane) so they compile to
// scalar s_load (lgkmcnt) and never serialize against the store vmcnt stream.
// 4 points unrolled per iteration -> 4 KiB of nontemporal float4 stores issued
// back-to-back per wave-group (output has no reuse; keep it out of L2).

#define OUT_F 256

typedef float v4f __attribute__((ext_vector_type(4)));

__global__ __launch_bounds__(256, 4) void gabor_kernel(
    const float* __restrict__ x,      // (P, 3)
    const float* __restrict__ W,      // (256, 3)
    const float* __restrict__ b,      // (256,)
    const float* __restrict__ mu,     // (256, 3)
    const float* __restrict__ gamma,  // (256,)
    float* __restrict__ out,          // (P, 256)
    int P)
{
    const int lane        = threadIdx.x & 63;
    const int waveInBlock = threadIdx.x >> 6;
    const int wavesPerBlk = blockDim.x >> 6;
    const int wavesTotal  = gridDim.x * wavesPerBlk;
    // Force wave-uniformity so x addressing is scalar (s_load, lgkmcnt).
    const int waveId = __builtin_amdgcn_readfirstlane(blockIdx.x * wavesPerBlk + waveInBlock);

    const int o = lane << 2;  // 4 consecutive out-features per lane

    // Per-feature constants live in registers for the whole kernel (~36 VGPRs).
    float w0[4], w1[4], w2[4], bb[4], m0[4], m1[4], m2[4], mu2s[4], gs[4];
#pragma unroll
    for (int j = 0; j < 4; ++j) {
        const int oj = o + j;
        w0[j] = W[oj * 3 + 0];
        w1[j] = W[oj * 3 + 1];
        w2[j] = W[oj * 3 + 2];
        m0[j] = mu[oj * 3 + 0];
        m1[j] = mu[oj * 3 + 1];
        m2[j] = mu[oj * 3 + 2];
        bb[j] = b[oj];
        gs[j] = -0.5f * gamma[oj];
        mu2s[j] = m0[j] * m0[j] + m1[j] * m1[j] + m2[j] * m2[j];
    }

    // Contiguous chunk of points per wave (x reads walk forward -> s_load merge).
    const int ppw  = (P + wavesTotal - 1) / wavesTotal;
    const int p0   = waveId * ppw;
    const int pend = (p0 + ppw < P) ? (p0 + ppw) : P;

    int p = p0;
    for (; p + 4 <= pend; p += 4) {
        // 12 wave-uniform scalar loads (4 points of x), issued before any compute.
        const float* xp = x + (size_t)p * 3;
        float xv[12];
#pragma unroll
        for (int i = 0; i < 12; ++i) xv[i] = xp[i];

        float* orow = out + (size_t)p * OUT_F + o;
#pragma unroll
        for (int q = 0; q < 4; ++q) {
            const float x0 = xv[q * 3 + 0];
            const float x1 = xv[q * 3 + 1];
            const float x2 = xv[q * 3 + 2];
            const float xs = x0 * x0 + x1 * x1 + x2 * x2;
            v4f r;
#pragma unroll
            for (int j = 0; j < 4; ++j) {
                const float lin   = fmaf(w0[j], x0, fmaf(w1[j], x1, fmaf(w2[j], x2, bb[j])));
                const float cross = fmaf(m0[j], x0, fmaf(m1[j], x1, m2[j] * x2));
                const float D     = xs - 2.0f * cross + mu2s[j];   // reference identity
                r[j] = __sinf(lin) * __expf(gs[j] * D);
            }
            __builtin_nontemporal_store(r, (v4f*)(orow + (size_t)q * OUT_F));
        }
    }
    // Tail (P is divisible in practice; kept for safety).
    for (; p < pend; ++p) {
        const float x0 = x[p * 3 + 0];
        const float x1 = x[p * 3 + 1];
        const float x2 = x[p * 3 + 2];
        const float xs = x0 * x0 + x1 * x1 + x2 * x2;
        v4f r;
#pragma unroll
        for (int j = 0; j < 4; ++j) {
            const float lin   = fmaf(w0[j], x0, fmaf(w1[j], x1, fmaf(w2[j], x2, bb[j])));
            const float cross = fmaf(m0[j], x0, fmaf(m1[j], x1, m2[j] * x2));
            const float D     = xs - 2.0f * cross + mu2s[j];
            r[j] = __sinf(lin) * __expf(gs[j] * D);
        }
        __builtin_nontemporal_store(r, (v4f*)(out + (size_t)p * OUT_F + o));
    }
}

extern "C" void kernel_launch(void* const* d_in, const int* in_sizes, int n_in,
                              void* d_out, int out_size, void* d_ws, size_t ws_size,
                              hipStream_t stream) {
    const float* x     = (const float*)d_in[0];
    const float* W     = (const float*)d_in[1];
    const float* b     = (const float*)d_in[2];
    const float* mu    = (const float*)d_in[3];
    const float* gamma = (const float*)d_in[4];
    float* out = (float*)d_out;

    const int P = in_sizes[0] / 3;  // B*N points

    // 2048 blocks x 4 waves = 8192 waves -> 32 contiguous points per wave.
    gabor_kernel<<<2048, 256, 0, stream>>>(x, W, b, mu, gamma, out, P);
}